// Round 1
// baseline (107.787 us; speedup 1.0000x reference)
//
#include <hip/hip_runtime.h>
#include <hip/hip_cooperative_groups.h>

namespace cg = cooperative_groups;

// FALCON ObjectSomeValuesFrom forward, product t-norm — single cooperative kernel.
//
// Identity (verified absmax 0.0 in the 2-kernel version):
//   r_fs[i,j]*c_fs[j] = sigmoid(row_i+col_j+b)*sigmoid(cw+col_j+b) is strictly
//   increasing in col_j  =>  argmax_j = argmax col_j, identical for every i.
//   out[i] = sigmoid(dl_i + rw + colmax + b) * sigmoid(cw + colmax + b)
// where dl_i = e_i·w_l, col_j = e_j·w_r, rw = r_emb·w_l, cw = c_emb·w_l.
//
// Phase 1: each of 256 blocks computes 32 row-dots (dl kept in LDS — no global
//          round-trip) and its partial col-max -> ws[blockIdx] (own slot, no
//          atomic, no init; ws fully rewritten each iter so poison-safe).
// grid.sync() (cooperative launch — one dispatch instead of two).
// Phase 2: every block reduces the 256 partials (1 KB, L2-broadcast), computes
//          the uniform cw/rw dots on 32 lanes, applies the two sigmoids to its
//          own 32 rows.

#define N_NAMED 8000
#define N_ALL   8192
#define D       128
#define NBLK    256
#define ROWS_PER_BLK (N_ALL / NBLK)   // 32

__global__ __launch_bounds__(256) void k_fused(
    const float* __restrict__ anon_e, const float* __restrict__ e_table,
    const float* __restrict__ c_table, const float* __restrict__ r_table,
    const float* __restrict__ fc0_w, const float* __restrict__ fc0_b,
    const int* __restrict__ c_id, const int* __restrict__ r_id,
    float* __restrict__ part, float* __restrict__ out)
{
    const int tid = threadIdx.x;
    const int g   = tid >> 5;          // 32-lane group 0..7
    const int l   = tid & 31;

    // weight chunks: w_l = fc0_w[0:128], w_r = fc0_w[128:256]
    const float4 wl = ((const float4*)fc0_w)[l];
    const float4 wr = ((const float4*)fc0_w)[32 + l];

    __shared__ float sdl[ROWS_PER_BLK];  // per-row e·w_l, survives grid sync
    __shared__ float sred[8];
    __shared__ float swm[4];
    __shared__ float s_cw, s_rw;

    // ---- phase 1: 4 passes × 8 rows/block-pass ----
    float dmax = -3.0e38f;
    #pragma unroll
    for (int p = 0; p < 4; p++) {
        const int row = blockIdx.x * ROWS_PER_BLK + p * 8 + g;
        const float4* rp = (row < N_NAMED)
            ? (const float4*)(e_table + (size_t)row * D)
            : (const float4*)(anon_e + (size_t)(row - N_NAMED) * D);
        float4 e = rp[l];
        float dl = e.x*wl.x + e.y*wl.y + e.z*wl.z + e.w*wl.w;
        float dr = e.x*wr.x + e.y*wr.y + e.z*wr.z + e.w*wr.w;
        #pragma unroll
        for (int off = 16; off >= 1; off >>= 1) {   // xor<32: stays in group
            dl += __shfl_xor(dl, off, 64);
            dr += __shfl_xor(dr, off, 64);
        }
        if (l == 0) sdl[p * 8 + g] = dl;
        dmax = fmaxf(dmax, dr);                      // all 32 lanes hold dr
    }
    if (l == 0) sred[g] = dmax;
    __syncthreads();
    if (tid == 0) {
        float m = sred[0];
        #pragma unroll
        for (int i = 1; i < 8; i++) m = fmaxf(m, sred[i]);
        part[blockIdx.x] = m;    // own slot — no atomic, no init dispatch
    }

    cg::this_grid().sync();

    // ---- phase 2: global col-max from 256 partials (1 KB, L2-broadcast) ----
    float m = part[tid];
    #pragma unroll
    for (int off = 32; off >= 1; off >>= 1)
        m = fmaxf(m, __shfl_xor(m, off, 64));
    if ((tid & 63) == 0) swm[tid >> 6] = m;

    // uniform cw/rw dots on the first 32 lanes (overlaps with swm writes)
    if (tid < 32) {
        const float4* cp = (const float4*)(c_table + (size_t)c_id[0] * D);
        const float4* rp = (const float4*)(r_table + (size_t)r_id[0] * D);
        float4 c4 = cp[l], r4 = rp[l];
        float cw = c4.x*wl.x + c4.y*wl.y + c4.z*wl.z + c4.w*wl.w;
        float rw = r4.x*wl.x + r4.y*wl.y + r4.z*wl.z + r4.w*wl.w;
        #pragma unroll
        for (int off = 16; off >= 1; off >>= 1) {
            cw += __shfl_xor(cw, off, 64);
            rw += __shfl_xor(rw, off, 64);
        }
        if (tid == 0) { s_cw = cw; s_rw = rw; }
    }
    __syncthreads();

    if (tid < ROWS_PER_BLK) {
        const float colmax = fmaxf(fmaxf(swm[0], swm[1]), fmaxf(swm[2], swm[3]));
        const float b  = fc0_b[0];
        const float s2 = 1.f / (1.f + __expf(-(s_cw + colmax + b)));
        const float a1 = sdl[tid] + s_rw + colmax + b;
        const float s1 = 1.f / (1.f + __expf(-a1));
        out[blockIdx.x * ROWS_PER_BLK + tid] = s1 * s2;
    }
}

extern "C" void kernel_launch(void* const* d_in, const int* in_sizes, int n_in,
                              void* d_out, int out_size, void* d_ws, size_t ws_size,
                              hipStream_t stream) {
    const float* anon_e  = (const float*)d_in[0];
    const float* e_table = (const float*)d_in[1];
    const float* c_table = (const float*)d_in[2];
    const float* r_table = (const float*)d_in[3];
    const float* fc0_w   = (const float*)d_in[4];
    const float* fc0_b   = (const float*)d_in[5];
    const int*   c_id    = (const int*)d_in[6];
    const int*   r_id    = (const int*)d_in[7];
    float* out = (float*)d_out;
    float* ws  = (float*)d_ws;   // 256 partial col-maxima (rewritten every iter)

    void* args[] = {
        (void*)&anon_e, (void*)&e_table, (void*)&c_table, (void*)&r_table,
        (void*)&fc0_w,  (void*)&fc0_b,   (void*)&c_id,    (void*)&r_id,
        (void*)&ws,     (void*)&out
    };
    hipLaunchCooperativeKernel((const void*)k_fused, dim3(NBLK), dim3(256),
                               args, 0, stream);
}

// Round 3
// 72.827 us; speedup vs baseline: 1.4800x; 1.4800x over previous
//
#include <hip/hip_runtime.h>

// FALCON ObjectSomeValuesFrom forward, product t-norm.
// Identity: r_fs[i,j]*c_fs[j] = sigmoid(row_i+col_j+b)*sigmoid(cw+col_j+b) is
// strictly increasing in col_j => argmax_j is argmax col_j, same for all i.
//   out[i] = sigmoid(rowdot_i + rw + colmax + b) * sigmoid(cw + colmax + b)
// K1: per-row dots (rowdot -> d_out) + per-block col-max -> ws[blockIdx]
//     (own-slot plain store: no atomic, no init dispatch needed).
// K2: each block reduces the 1024 partial maxima (4 KB, L2-hit), computes the
//     uniform cw/rw dots (32-lane vectorized — no serial 128-FMA chain),
//     applies the two sigmoids elementwise.
// NOTE: plain kernel launches only — hipLaunchCooperativeKernel breaks hip
// graph capture and cost +32 us/iter (measured round 1).

#define N_NAMED 8000
#define N_ALL   8192
#define D       128
#define K1_BLOCKS (N_ALL / 8)   // 1024 blocks, 8 rows/block

__global__ __launch_bounds__(256) void k_dots(
    const float* __restrict__ anon_e, const float* __restrict__ e_table,
    const float* __restrict__ fc0_w, float* __restrict__ rowdot,
    float* __restrict__ colmax_part)
{
    const int tid = threadIdx.x;
    const int g   = tid >> 5;          // 32-lane group 0..7
    const int l   = tid & 31;
    const int row = blockIdx.x * 8 + g;

    const float4* rp = (row < N_NAMED)
        ? (const float4*)(e_table + (size_t)row * D)
        : (const float4*)(anon_e + (size_t)(row - N_NAMED) * D);

    float4 e  = rp[l];
    float4 wl = ((const float4*)fc0_w)[l];        // w_l chunk
    float4 wr = ((const float4*)fc0_w)[32 + l];   // w_r chunk

    float dl = e.x*wl.x + e.y*wl.y + e.z*wl.z + e.w*wl.w;
    float dr = e.x*wr.x + e.y*wr.y + e.z*wr.z + e.w*wr.w;

    #pragma unroll
    for (int off = 16; off >= 1; off >>= 1) {   // xor<32: stays in 32-lane group
        dl += __shfl_xor(dl, off, 64);
        dr += __shfl_xor(dr, off, 64);
    }

    __shared__ float scol[8];
    if (l == 0) { rowdot[row] = dl; scol[g] = dr; }
    __syncthreads();
    if (tid == 0) {
        float m = scol[0];
        #pragma unroll
        for (int i = 1; i < 8; i++) m = fmaxf(m, scol[i]);
        colmax_part[blockIdx.x] = m;   // own slot — no init, no atomic
    }
}

__global__ __launch_bounds__(256) void k_final(
    const float* __restrict__ c_table, const float* __restrict__ r_table,
    const float* __restrict__ fc0_w, const float* __restrict__ fc0_b,
    const int* __restrict__ c_id, const int* __restrict__ r_id,
    const float* __restrict__ colmax_part, float* __restrict__ out)
{
    const int tid = threadIdx.x;
    const int l   = tid & 31;
    const int i   = blockIdx.x * 256 + tid;

    // block-local reduction of the 1024 partial maxima (L2-resident, 4 KB)
    float m = colmax_part[tid];
    m = fmaxf(m, colmax_part[tid + 256]);
    m = fmaxf(m, colmax_part[tid + 512]);
    m = fmaxf(m, colmax_part[tid + 768]);
    #pragma unroll
    for (int off = 32; off >= 1; off >>= 1)
        m = fmaxf(m, __shfl_xor(m, off, 64));

    __shared__ float swm[4];
    __shared__ float smax, s_cw, s_rw;
    if ((tid & 63) == 0) swm[tid >> 6] = m;

    // uniform cw/rw dots on 32 lanes (vectorized — kills the 128-step
    // dependent scalar FMA chain of the previous version)
    if (tid < 32) {
        const float4* cp = (const float4*)(c_table + (size_t)c_id[0] * D);
        const float4* rp = (const float4*)(r_table + (size_t)r_id[0] * D);
        const float4  wl = ((const float4*)fc0_w)[l];
        float4 c4 = cp[l], r4 = rp[l];
        float cw = c4.x*wl.x + c4.y*wl.y + c4.z*wl.z + c4.w*wl.w;
        float rw = r4.x*wl.x + r4.y*wl.y + r4.z*wl.z + r4.w*wl.w;
        #pragma unroll
        for (int off = 16; off >= 1; off >>= 1) {
            cw += __shfl_xor(cw, off, 64);
            rw += __shfl_xor(rw, off, 64);
        }
        if (tid == 0) { s_cw = cw; s_rw = rw; }
    }
    __syncthreads();
    if (tid == 0)
        smax = fmaxf(fmaxf(swm[0], swm[1]), fmaxf(swm[2], swm[3]));
    __syncthreads();

    const float colmax = smax;
    const float b  = fc0_b[0];
    const float a1 = out[i] + s_rw + colmax + b;
    const float a2 = s_cw + colmax + b;
    const float s1 = 1.f / (1.f + __expf(-a1));
    const float s2 = 1.f / (1.f + __expf(-a2));
    out[i] = s1 * s2;
}

extern "C" void kernel_launch(void* const* d_in, const int* in_sizes, int n_in,
                              void* d_out, int out_size, void* d_ws, size_t ws_size,
                              hipStream_t stream) {
    const float* anon_e  = (const float*)d_in[0];
    const float* e_table = (const float*)d_in[1];
    const float* c_table = (const float*)d_in[2];
    const float* r_table = (const float*)d_in[3];
    const float* fc0_w   = (const float*)d_in[4];
    const float* fc0_b   = (const float*)d_in[5];
    const int*   c_id    = (const int*)d_in[6];
    const int*   r_id    = (const int*)d_in[7];
    float* out = (float*)d_out;
    float* ws  = (float*)d_ws;   // 1024 partial col-maxima

    k_dots<<<K1_BLOCKS, 256, 0, stream>>>(anon_e, e_table, fc0_w, out, ws);
    k_final<<<N_ALL / 256, 256, 0, stream>>>(c_table, r_table, fc0_w, fc0_b,
                                             c_id, r_id, ws, out);
}